// Round 5
// baseline (364.323 us; speedup 1.0000x reference)
//
#include <hip/hip_runtime.h>
#include <hip/hip_bf16.h>

// ScaledDotProductAttention: B=1 H=16 S=4096 D=64, fp32 in/out.
// Outputs: [out (16,4096,64) | attn (16,4096,4096)] concatenated in d_out.
//
// bf16 MFMA 16x16x32, two-pass softmax per 128-row block:
//   pass 1: S^T = K(Q/8·log2e)^T, rowsum += exp2(S')
//   pass 2: recompute S^T, P = exp2(S')*inv, write attn (dwordx4 NT), O += P@V
// Swapped operands (A=K, B=Q): lane holds 4 consecutive keys -> vector stores.
// Double-buffered LDS staging, ONE barrier per tile.
//
// R4: NT attn/out stores (kept: −50us, L2 thrash was real but secondary).
// R5: raw s_barrier with lgkmcnt(0)-ONLY drain. __syncthreads() emits
// s_waitcnt vmcnt(0) before s_barrier, which (a) stalled every tile on the
// *prefetch* loads for kt+1 (full L2/HBM latency exposed, prefetch inverted
// into a stall) and (b) drained the NT store queue per tile. LDS visibility
// only needs lgkmcnt(0); counted vmcnt waits at the staging writes let loads
// overlap compute and stores drain in background.

#define NH  16
#define SEQ 4096
#define DH  64
#define BM  128
#define BN  64
#define NKT (SEQ / BN)   // 64 key tiles
#define NRB (SEQ / BM)   // 32 row blocks per head
#define NT  512          // 8 waves

typedef __attribute__((ext_vector_type(8))) short bf16x8;
typedef __attribute__((ext_vector_type(4))) float f32x4;

// round-to-nearest-even f32 -> bf16
static __device__ __forceinline__ unsigned short f2bf(float f) {
  unsigned x = __float_as_uint(f);
  return (unsigned short)((x + 0x7fffu + ((x >> 16) & 1u)) >> 16);
}

// barrier that does NOT drain vmcnt: LDS-visibility only.
static __device__ __forceinline__ void bar_lgkm() {
  asm volatile("s_waitcnt lgkmcnt(0)" ::: "memory");
  __builtin_amdgcn_s_barrier();
  asm volatile("" ::: "memory");   // compiler fence: keep ds_reads after barrier
}

// XOR-swizzled element index in a [R][64] bf16 LDS tile (breaks the 128B-row
// bank conflict; XOR touches element bits 3..5 so 4/8-elem packs stay intact).
static __device__ __forceinline__ int swz(int row, int col) {
  return row * 64 + (col ^ ((row & 7) << 3));
}

// Layouts (verified by round-0/1 passes):
//   A-frag: row = lane&15, k = 8*(lane>>4)+j ; B-frag: col = lane&15, same k
//   C/D:    col = lane&15, row = 4*(lane>>4)+reg
// With A=K, B=Q:  C[key_local][q_local] -> lane holds q=r16, keys 4*g4+reg.

__global__ __launch_bounds__(NT, 4)   // 4 waves/SIMD -> VGPR<=128, 2 blocks/CU
void attn_fused(const float* __restrict__ q, const float* __restrict__ kg,
                const float* __restrict__ vg, float* __restrict__ out,
                float* __restrict__ attn)
{
  __shared__ __align__(16) unsigned short Ks[2][64 * 64];   // [key][d] bf16, swizzled
  __shared__ __align__(16) unsigned short Vt[2][64 * 64];   // [d][key] bf16, swizzled
  __shared__ __align__(16) unsigned short Pb[8][16 * 64];   // per-wave P [row][key]

  const int nwg = NH * NRB;  // 512
  int bid = blockIdx.x;
  int wg = (bid & 7) * (nwg >> 3) + (bid >> 3);   // XCD swizzle (bijective: 512%8==0)
  const int h    = wg >> 5;
  const int row0 = (wg & (NRB - 1)) * BM;

  const int t    = threadIdx.x;
  const int lane = t & 63;
  const int wid  = t >> 6;
  const int r16  = lane & 15;
  const int g4   = lane >> 4;

  const float* qh = q  + (size_t)h * SEQ * DH;
  const float* kh = kg + (size_t)h * SEQ * DH;
  const float* vh = vg + (size_t)h * SEQ * DH;

  const int kKey = t >> 4;         // 0..31 (+32 for i=1)
  const int kD   = (t & 15) * 4;
  const int vKey = t & 31;         // (+32 for i=1)
  const int vD   = (t >> 5) * 4;

  // ---- Q as B-fragments, pre-scaled by 0.125*log2(e) so softmax uses exp2
  const float QS = 0.125f * 1.44269504088896340736f;
  bf16x8 qa[2];
  #pragma unroll
  for (int kf = 0; kf < 2; ++kf) {
    const float* qp = qh + (size_t)(row0 + wid * 16 + r16) * DH + kf * 32 + g4 * 8;
    float4 x0 = *(const float4*)qp;
    float4 x1 = *(const float4*)(qp + 4);
    bf16x8 a;
    a[0] = (short)f2bf(x0.x * QS); a[1] = (short)f2bf(x0.y * QS);
    a[2] = (short)f2bf(x0.z * QS); a[3] = (short)f2bf(x0.w * QS);
    a[4] = (short)f2bf(x1.x * QS); a[5] = (short)f2bf(x1.y * QS);
    a[6] = (short)f2bf(x1.z * QS); a[7] = (short)f2bf(x1.w * QS);
    qa[kf] = a;
  }

  // ================= PASS 1: rowsums of exp2(S') =================
  float rsum = 0.f;
  float4 kr[2];
  #pragma unroll
  for (int i = 0; i < 2; ++i)
    kr[i] = *(const float4*)(kh + (size_t)(kKey + 32 * i) * DH + kD);

  #pragma unroll 1
  for (int kt = 0; kt < NKT; ++kt) {
    const int b = kt & 1;
    #pragma unroll
    for (int i = 0; i < 2; ++i)
      *(short4*)&Ks[b][swz(kKey + 32 * i, kD)] =
          make_short4((short)f2bf(kr[i].x), (short)f2bf(kr[i].y),
                      (short)f2bf(kr[i].z), (short)f2bf(kr[i].w));
    if (kt + 1 < NKT) {
      #pragma unroll
      for (int i = 0; i < 2; ++i)
        kr[i] = *(const float4*)(kh + (size_t)((kt + 1) * BN + kKey + 32 * i) * DH + kD);
    }
    bar_lgkm();
    #pragma unroll
    for (int n = 0; n < 4; ++n) {
      bf16x8 a0 = *(const bf16x8*)&Ks[b][swz(n * 16 + r16, g4 * 8)];
      bf16x8 a1 = *(const bf16x8*)&Ks[b][swz(n * 16 + r16, 32 + g4 * 8)];
      f32x4 c = {0.f, 0.f, 0.f, 0.f};
      c = __builtin_amdgcn_mfma_f32_16x16x32_bf16(a0, qa[0], c, 0, 0, 0);
      c = __builtin_amdgcn_mfma_f32_16x16x32_bf16(a1, qa[1], c, 0, 0, 0);
      #pragma unroll
      for (int r = 0; r < 4; ++r) rsum += __builtin_amdgcn_exp2f(c[r]);
    }
  }

  rsum += __shfl_xor(rsum, 16);
  rsum += __shfl_xor(rsum, 32);
  const float inv = 1.0f / rsum;

  // ================= PASS 2: attn write + O = P@V =================
  f32x4 accO[4];
  #pragma unroll
  for (int n = 0; n < 4; ++n) accO[n] = (f32x4){0.f, 0.f, 0.f, 0.f};

  float4 kr2[2], vr[2];
  #pragma unroll
  for (int i = 0; i < 2; ++i) {
    kr2[i] = *(const float4*)(kh + (size_t)(kKey + 32 * i) * DH + kD);
    vr[i]  = *(const float4*)(vh + (size_t)(vKey + 32 * i) * DH + vD);
  }
  __syncthreads();   // pass boundary (once; full drain harmless here)

  float* aprow = attn + (size_t)(h * SEQ + row0 + wid * 16 + r16) * SEQ;

  #pragma unroll 1
  for (int kt = 0; kt < NKT; ++kt) {
    const int b = kt & 1;
    #pragma unroll
    for (int i = 0; i < 2; ++i) {
      *(short4*)&Ks[b][swz(kKey + 32 * i, kD)] =
          make_short4((short)f2bf(kr2[i].x), (short)f2bf(kr2[i].y),
                      (short)f2bf(kr2[i].z), (short)f2bf(kr2[i].w));
      Vt[b][swz(vD + 0, vKey + 32 * i)] = f2bf(vr[i].x);
      Vt[b][swz(vD + 1, vKey + 32 * i)] = f2bf(vr[i].y);
      Vt[b][swz(vD + 2, vKey + 32 * i)] = f2bf(vr[i].z);
      Vt[b][swz(vD + 3, vKey + 32 * i)] = f2bf(vr[i].w);
    }
    if (kt + 1 < NKT) {
      #pragma unroll
      for (int i = 0; i < 2; ++i) {
        kr2[i] = *(const float4*)(kh + (size_t)((kt + 1) * BN + kKey + 32 * i) * DH + kD);
        vr[i]  = *(const float4*)(vh + (size_t)((kt + 1) * BN + vKey + 32 * i) * DH + vD);
      }
    }
    bar_lgkm();

    // S^T tile -> P; NT vector attn store; stage P for PV
    #pragma unroll
    for (int n = 0; n < 4; ++n) {
      bf16x8 a0 = *(const bf16x8*)&Ks[b][swz(n * 16 + r16, g4 * 8)];
      bf16x8 a1 = *(const bf16x8*)&Ks[b][swz(n * 16 + r16, 32 + g4 * 8)];
      f32x4 c = {0.f, 0.f, 0.f, 0.f};
      c = __builtin_amdgcn_mfma_f32_16x16x32_bf16(a0, qa[0], c, 0, 0, 0);
      c = __builtin_amdgcn_mfma_f32_16x16x32_bf16(a1, qa[1], c, 0, 0, 0);
      f32x4 p;
      p[0] = __builtin_amdgcn_exp2f(c[0]) * inv;
      p[1] = __builtin_amdgcn_exp2f(c[1]) * inv;
      p[2] = __builtin_amdgcn_exp2f(c[2]) * inv;
      p[3] = __builtin_amdgcn_exp2f(c[3]) * inv;
      __builtin_nontemporal_store(p, (f32x4*)(aprow + (size_t)kt * BN + n * 16 + g4 * 4));
      *(short4*)&Pb[wid][swz(r16, n * 16 + g4 * 4)] =
          make_short4((short)f2bf(p[0]), (short)f2bf(p[1]),
                      (short)f2bf(p[2]), (short)f2bf(p[3]));
    }
    // PV: A = P[q=r16][keys 8g4+j] from wave-private LDS (in-order DS pipe)
    bf16x8 pa0 = *(const bf16x8*)&Pb[wid][swz(r16, g4 * 8)];
    bf16x8 pa1 = *(const bf16x8*)&Pb[wid][swz(r16, 32 + g4 * 8)];
    #pragma unroll
    for (int n = 0; n < 4; ++n) {
      bf16x8 v0 = *(const bf16x8*)&Vt[b][swz(n * 16 + r16, g4 * 8)];
      bf16x8 v1 = *(const bf16x8*)&Vt[b][swz(n * 16 + r16, 32 + g4 * 8)];
      accO[n] = __builtin_amdgcn_mfma_f32_16x16x32_bf16(pa0, v0, accO[n], 0, 0, 0);
      accO[n] = __builtin_amdgcn_mfma_f32_16x16x32_bf16(pa1, v1, accO[n], 0, 0, 0);
    }
  }

  // ---- epilogue: write O (16.8 MB, NT scalar stores)
  #pragma unroll
  for (int n = 0; n < 4; ++n) {
    #pragma unroll
    for (int r = 0; r < 4; ++r) {
      __builtin_nontemporal_store(accO[n][r],
          out + (size_t)(h * SEQ + row0 + wid * 16 + g4 * 4 + r) * DH + n * 16 + r16);
    }
  }
}

extern "C" void kernel_launch(void* const* d_in, const int* in_sizes, int n_in,
                              void* d_out, int out_size, void* d_ws, size_t ws_size,
                              hipStream_t stream) {
  const float* q = (const float*)d_in[0];
  const float* k = (const float*)d_in[1];
  const float* v = (const float*)d_in[2];
  float* out  = (float*)d_out;
  float* attn = out + (size_t)NH * SEQ * DH;   // [out | attn] concatenated
  hipLaunchKernelGGL(attn_fused, dim3(NH * NRB), dim3(NT), 0, stream,
                     q, k, v, out, attn);
}